// Round 8
// baseline (246.071 us; speedup 1.0000x reference)
//
#include <hip/hip_runtime.h>

#define N_NODES 50000
#define N_EDGES 800000
#define D_FEAT 96
#define HOP_NUM 4
#define OUT_STRIDE (HOP_NUM * D_FEAT)
#define SCAN_B 256
#define NBLK_SCAN ((N_NODES + SCAN_B - 1) / SCAN_B)  // 196
#define EB_BLOCKS ((N_EDGES + 255) / 256)            // 3125
#define F2B_VEC (N_NODES * D_FEAT / 4)               // 1.2M float4s

#define GROUP 24            // one lane per ushort4 chunk of a 96-ch row
#define GPB 8               // groups per block
#define HOP_BLOCK (GROUP * GPB)  // 192 threads = exactly 3 waves

struct Edge { int s; float w; };

__device__ __forceinline__ unsigned short f2bf(float x) {
    union { float f; unsigned u; } c; c.f = x;
    unsigned r = (c.u + 0x7FFFu + ((c.u >> 16) & 1u)) >> 16;  // RNE
    return (unsigned short)r;
}
__device__ __forceinline__ float bf2f(unsigned short b) {
    union { unsigned u; float f; } c; c.u = ((unsigned)b) << 16;
    return c.f;
}

// ---------- CSR build (once per launch) ----------

__global__ void zero_deg_kernel(int* __restrict__ deg) {
    int i = blockIdx.x * blockDim.x + threadIdx.x;
    if (i < N_NODES) deg[i] = 0;
}

__global__ void hist_kernel(const int* __restrict__ dst, int* __restrict__ deg) {
    int e = blockIdx.x * blockDim.x + threadIdx.x;
    if (e >= N_EDGES) return;
    atomicAdd(&deg[dst[e]], 1);
}

// Per-block exclusive scan of deg into off (block-local), block totals -> partials.
// Also zeroes the scatter cursor and sets off[N_NODES] (block-local inclusive).
__global__ void scanA_kernel(const int* __restrict__ deg, int* __restrict__ off,
                             int* __restrict__ partials, int* __restrict__ cursor) {
    int i = blockIdx.x * SCAN_B + threadIdx.x;
    int v = (i < N_NODES) ? deg[i] : 0;
    int lane = threadIdx.x & 63;
    int wid  = threadIdx.x >> 6;
    int x = v;
    #pragma unroll
    for (int o = 1; o < 64; o <<= 1) {
        int y = __shfl_up(x, o, 64);
        if (lane >= o) x += y;
    }
    __shared__ int wtot[SCAN_B / 64];
    if (lane == 63) wtot[wid] = x;
    __syncthreads();
    int wbase = 0;
    #pragma unroll
    for (int w = 0; w < SCAN_B / 64; ++w) wbase += (w < wid) ? wtot[w] : 0;
    if (i < N_NODES) {
        off[i] = wbase + x - v;   // block-local exclusive
        cursor[i] = 0;
    }
    if (i == N_NODES - 1) off[N_NODES] = wbase + x;
    if (threadIdx.x == SCAN_B - 1) partials[blockIdx.x] = wbase + x;
}

// Single block scans the 196 block totals (exclusive, in place).
__global__ void scanB_kernel(int* __restrict__ partials) {
    int tid = threadIdx.x;  // 256 threads
    int v = (tid < NBLK_SCAN) ? partials[tid] : 0;
    int lane = tid & 63;
    int wid  = tid >> 6;
    int x = v;
    #pragma unroll
    for (int o = 1; o < 64; o <<= 1) {
        int y = __shfl_up(x, o, 64);
        if (lane >= o) x += y;
    }
    __shared__ int wtot[SCAN_B / 64];
    if (lane == 63) wtot[wid] = x;
    __syncthreads();
    int wbase = 0;
    #pragma unroll
    for (int w = 0; w < SCAN_B / 64; ++w) wbase += (w < wid) ? wtot[w] : 0;
    if (tid < NBLK_SCAN) partials[tid] = wbase + x - v;
}

__global__ void scatter_kernel(const int* __restrict__ src, const int* __restrict__ dst,
                               const float* __restrict__ dn,
                               const int* __restrict__ off, const int* __restrict__ partials,
                               int* __restrict__ cursor, Edge* __restrict__ edges) {
    int e = blockIdx.x * blockDim.x + threadIdx.x;
    if (e >= N_EDGES) return;
    int t = dst[e];
    int s = src[e];
    float w = dn[s] * dn[t];
    int p = atomicAdd(&cursor[t], 1);
    Edge ed; ed.s = s; ed.w = w;
    edges[off[t] + partials[t >> 8] + p] = ed;
}

// seed: f32 features -> bf16 table
__global__ void f32_to_bf16_kernel(const float* __restrict__ in, unsigned short* __restrict__ out) {
    int i = blockIdx.x * blockDim.x + threadIdx.x;
    if (i >= F2B_VEC) return;
    float4 v = ((const float4*)in)[i];
    ushort4 o;
    o.x = f2bf(v.x); o.y = f2bf(v.y); o.z = f2bf(v.z); o.w = f2bf(v.w);
    ((ushort4*)out)[i] = o;
}

// ---------- fused per-hop SpMM + residual blend (bf16 gather table) ----------
// 24-lane group per dst node, 100% lane utilization, no shuffles: every lane
// loads the same Edge (broadcast transaction) and gathers its own ushort4.
__global__ void __launch_bounds__(HOP_BLOCK)
spmm_gather_kernel(const unsigned short* __restrict__ tab,
                   const int* __restrict__ off,
                   const int* __restrict__ partials,
                   const Edge* __restrict__ edges,
                   const float* __restrict__ lr, int hop,
                   float* __restrict__ out,
                   unsigned short* __restrict__ tab_next) {
    int t = blockIdx.x * HOP_BLOCK + threadIdx.x;
    int gid = t / GROUP;
    int lane = t % GROUP;
    if (gid >= N_NODES) return;
    int beg = off[gid] + partials[gid >> 8];
    int end = off[gid + 1] + partials[(gid + 1) >> 8];

    float4 acc = make_float4(0.f, 0.f, 0.f, 0.f);
    int k = beg;
    for (; k + 4 <= end; k += 4) {
        Edge e0 = edges[k];
        Edge e1 = edges[k + 1];
        Edge e2 = edges[k + 2];
        Edge e3 = edges[k + 3];
        ushort4 u0 = ((const ushort4*)(tab + (long long)e0.s * D_FEAT))[lane];
        ushort4 u1 = ((const ushort4*)(tab + (long long)e1.s * D_FEAT))[lane];
        ushort4 u2 = ((const ushort4*)(tab + (long long)e2.s * D_FEAT))[lane];
        ushort4 u3 = ((const ushort4*)(tab + (long long)e3.s * D_FEAT))[lane];
        acc.x = fmaf(bf2f(u0.x), e0.w, fmaf(bf2f(u1.x), e1.w, fmaf(bf2f(u2.x), e2.w, fmaf(bf2f(u3.x), e3.w, acc.x))));
        acc.y = fmaf(bf2f(u0.y), e0.w, fmaf(bf2f(u1.y), e1.w, fmaf(bf2f(u2.y), e2.w, fmaf(bf2f(u3.y), e3.w, acc.y))));
        acc.z = fmaf(bf2f(u0.z), e0.w, fmaf(bf2f(u1.z), e1.w, fmaf(bf2f(u2.z), e2.w, fmaf(bf2f(u3.z), e3.w, acc.z))));
        acc.w = fmaf(bf2f(u0.w), e0.w, fmaf(bf2f(u1.w), e1.w, fmaf(bf2f(u2.w), e2.w, fmaf(bf2f(u3.w), e3.w, acc.w))));
    }
    for (; k < end; ++k) {
        Edge e = edges[k];
        ushort4 u = ((const ushort4*)(tab + (long long)e.s * D_FEAT))[lane];
        acc.x = fmaf(bf2f(u.x), e.w, acc.x);
        acc.y = fmaf(bf2f(u.y), e.w, acc.y);
        acc.z = fmaf(bf2f(u.z), e.w, acc.z);
        acc.w = fmaf(bf2f(u.w), e.w, acc.w);
    }

    float r = lr[hop];
    ushort4 pu = ((const ushort4*)(tab + (long long)gid * D_FEAT))[lane];
    float4 o;
    o.x = acc.x * r + (1.0f - r) * bf2f(pu.x);
    o.y = acc.y * r + (1.0f - r) * bf2f(pu.y);
    o.z = acc.z * r + (1.0f - r) * bf2f(pu.z);
    o.w = acc.w * r + (1.0f - r) * bf2f(pu.w);
    ((float4*)(out + (long long)gid * OUT_STRIDE))[lane] = o;
    if (tab_next) {
        ushort4 ov;
        ov.x = f2bf(o.x); ov.y = f2bf(o.y); ov.z = f2bf(o.z); ov.w = f2bf(o.w);
        ((ushort4*)(tab_next + (long long)gid * D_FEAT))[lane] = ov;
    }
}

extern "C" void kernel_launch(void* const* d_in, const int* in_sizes, int n_in,
                              void* d_out, int out_size, void* d_ws, size_t ws_size,
                              hipStream_t stream) {
    const float* h   = (const float*)d_in[0];
    const float* dn  = (const float*)d_in[1];
    const int*   src = (const int*)d_in[2];
    const int*   dst = (const int*)d_in[3];
    const float* lr  = (const float*)d_in[4];
    float* out = (float*)d_out;

    // workspace carve-up (16B-aligned chunks first)
    char* base = (char*)d_ws;
    Edge* edges = (Edge*)base;                    base += (size_t)N_EDGES * sizeof(Edge);
    unsigned short* tabA = (unsigned short*)base; base += (size_t)N_NODES * D_FEAT * sizeof(unsigned short);
    unsigned short* tabB = (unsigned short*)base; base += (size_t)N_NODES * D_FEAT * sizeof(unsigned short);
    int* off      = (int*)base;                   base += (N_NODES + 1) * sizeof(int);
    int* deg      = (int*)base;                   base += N_NODES * sizeof(int);
    int* cursor   = (int*)base;                   base += N_NODES * sizeof(int);
    int* partials = (int*)base;                   base += NBLK_SCAN * sizeof(int);

    zero_deg_kernel<<<NBLK_SCAN, SCAN_B, 0, stream>>>(deg);
    hist_kernel<<<EB_BLOCKS, 256, 0, stream>>>(dst, deg);
    scanA_kernel<<<NBLK_SCAN, SCAN_B, 0, stream>>>(deg, off, partials, cursor);
    scanB_kernel<<<1, SCAN_B, 0, stream>>>(partials);
    scatter_kernel<<<EB_BLOCKS, 256, 0, stream>>>(src, dst, dn, off, partials, cursor, edges);
    f32_to_bf16_kernel<<<(F2B_VEC + 255) / 256, 256, 0, stream>>>(h, tabA);

    // 4 fused hops (bf16 ping-pong tables)
    const int HB = (N_NODES + GPB - 1) / GPB;  // 6250 blocks of 192 threads
    unsigned short* cur = tabA;
    unsigned short* nxt = tabB;
    for (int hop = 0; hop < HOP_NUM; ++hop) {
        unsigned short* wr = (hop == HOP_NUM - 1) ? (unsigned short*)nullptr : nxt;
        spmm_gather_kernel<<<HB, HOP_BLOCK, 0, stream>>>(cur, off, partials, edges, lr, hop,
                                                         out + hop * D_FEAT, wr);
        unsigned short* t = cur; cur = nxt; nxt = t;
    }
}

// Round 9
// 219.464 us; speedup vs baseline: 1.1212x; 1.1212x over previous
//
#include <hip/hip_runtime.h>

#define N_NODES 50000
#define N_EDGES 800000
#define D_FEAT 96
#define HOP_NUM 4
#define OUT_STRIDE (HOP_NUM * D_FEAT)
#define SCAN_B 256
#define NBLK_SCAN ((N_NODES + SCAN_B - 1) / SCAN_B)  // 196
#define EB_BLOCKS ((N_EDGES + 255) / 256)            // 3125
#define F2B_VEC (N_NODES * D_FEAT / 4)               // 1.2M float4s

#define GROUP 24            // one lane per ushort4 chunk of a 96-ch row
#define GPB 8               // groups per block
#define HOP_BLOCK (GROUP * GPB)  // 192 threads = exactly 3 waves

struct Edge { int s; float w; };

__device__ __forceinline__ unsigned short f2bf(float x) {
    union { float f; unsigned u; } c; c.f = x;
    unsigned r = (c.u + 0x7FFFu + ((c.u >> 16) & 1u)) >> 16;  // RNE
    return (unsigned short)r;
}
__device__ __forceinline__ float bf2f(unsigned short b) {
    union { unsigned u; float f; } c; c.u = ((unsigned)b) << 16;
    return c.f;
}

// ---------- CSR build (once per launch) ----------

__global__ void zero_deg_kernel(int* __restrict__ deg) {
    int i = blockIdx.x * blockDim.x + threadIdx.x;
    if (i < N_NODES) deg[i] = 0;
}

__global__ void hist_kernel(const int* __restrict__ dst, int* __restrict__ deg) {
    int e = blockIdx.x * blockDim.x + threadIdx.x;
    if (e >= N_EDGES) return;
    atomicAdd(&deg[dst[e]], 1);
}

// Phase A: per-block exclusive scan of deg into off (block-local), totals -> partials.
__global__ void scanA_kernel(const int* __restrict__ deg, int* __restrict__ off,
                             int* __restrict__ partials) {
    int i = blockIdx.x * SCAN_B + threadIdx.x;
    int v = (i < N_NODES) ? deg[i] : 0;
    int lane = threadIdx.x & 63;
    int wid  = threadIdx.x >> 6;
    int x = v;
    #pragma unroll
    for (int o = 1; o < 64; o <<= 1) {
        int y = __shfl_up(x, o, 64);
        if (lane >= o) x += y;
    }
    __shared__ int wtot[SCAN_B / 64];
    if (lane == 63) wtot[wid] = x;
    __syncthreads();
    int wbase = 0;
    #pragma unroll
    for (int w = 0; w < SCAN_B / 64; ++w) wbase += (w < wid) ? wtot[w] : 0;
    if (i < N_NODES) off[i] = wbase + x - v;
    if (threadIdx.x == SCAN_B - 1) partials[blockIdx.x] = wbase + x;
}

// Phase B: single block scans the 196 partials (exclusive, in place).
__global__ void scanB_kernel(int* __restrict__ partials) {
    int tid = threadIdx.x;  // 256 threads
    int v = (tid < NBLK_SCAN) ? partials[tid] : 0;
    int lane = tid & 63;
    int wid  = tid >> 6;
    int x = v;
    #pragma unroll
    for (int o = 1; o < 64; o <<= 1) {
        int y = __shfl_up(x, o, 64);
        if (lane >= o) x += y;
    }
    __shared__ int wtot[SCAN_B / 64];
    if (lane == 63) wtot[wid] = x;
    __syncthreads();
    int wbase = 0;
    #pragma unroll
    for (int w = 0; w < SCAN_B / 64; ++w) wbase += (w < wid) ? wtot[w] : 0;
    if (tid < NBLK_SCAN) partials[tid] = wbase + x - v;
}

// Phase C: add block bases -> GLOBAL offsets; zero the scatter cursor; off[N] = E.
__global__ void scanC_kernel(int* __restrict__ off, const int* __restrict__ partials,
                             int* __restrict__ cursor) {
    int i = blockIdx.x * SCAN_B + threadIdx.x;
    if (i < N_NODES) {
        off[i] += partials[blockIdx.x];
        cursor[i] = 0;
    }
    if (i == 0) off[N_NODES] = N_EDGES;
}

// scatter with GLOBAL offsets: store address = off[t] + p (single loaded base).
__global__ void scatter_kernel(const int* __restrict__ src, const int* __restrict__ dst,
                               const float* __restrict__ dn,
                               const int* __restrict__ off, int* __restrict__ cursor,
                               Edge* __restrict__ edges) {
    int e = blockIdx.x * blockDim.x + threadIdx.x;
    if (e >= N_EDGES) return;
    int t = dst[e];
    int s = src[e];
    float w = dn[s] * dn[t];
    int p = atomicAdd(&cursor[t], 1);
    Edge ed; ed.s = s; ed.w = w;
    edges[off[t] + p] = ed;
}

// seed: f32 features -> bf16 table
__global__ void f32_to_bf16_kernel(const float* __restrict__ in, unsigned short* __restrict__ out) {
    int i = blockIdx.x * blockDim.x + threadIdx.x;
    if (i >= F2B_VEC) return;
    float4 v = ((const float4*)in)[i];
    ushort4 o;
    o.x = f2bf(v.x); o.y = f2bf(v.y); o.z = f2bf(v.z); o.w = f2bf(v.w);
    ((ushort4*)out)[i] = o;
}

// ---------- fused per-hop SpMM + residual blend (bf16 gather table) ----------
// 24-lane group per dst node, 100% lane utilization, no shuffles: every lane
// loads the same Edge (broadcast transaction) and gathers its own ushort4.
__global__ void __launch_bounds__(HOP_BLOCK)
spmm_gather_kernel(const unsigned short* __restrict__ tab,
                   const int* __restrict__ off,
                   const Edge* __restrict__ edges,
                   const float* __restrict__ lr, int hop,
                   float* __restrict__ out,
                   unsigned short* __restrict__ tab_next) {
    int t = blockIdx.x * HOP_BLOCK + threadIdx.x;
    int gid = t / GROUP;
    int lane = t % GROUP;
    if (gid >= N_NODES) return;
    int beg = off[gid];
    int end = off[gid + 1];

    float4 acc = make_float4(0.f, 0.f, 0.f, 0.f);
    int k = beg;
    for (; k + 4 <= end; k += 4) {
        Edge e0 = edges[k];
        Edge e1 = edges[k + 1];
        Edge e2 = edges[k + 2];
        Edge e3 = edges[k + 3];
        ushort4 u0 = ((const ushort4*)(tab + (long long)e0.s * D_FEAT))[lane];
        ushort4 u1 = ((const ushort4*)(tab + (long long)e1.s * D_FEAT))[lane];
        ushort4 u2 = ((const ushort4*)(tab + (long long)e2.s * D_FEAT))[lane];
        ushort4 u3 = ((const ushort4*)(tab + (long long)e3.s * D_FEAT))[lane];
        acc.x = fmaf(bf2f(u0.x), e0.w, fmaf(bf2f(u1.x), e1.w, fmaf(bf2f(u2.x), e2.w, fmaf(bf2f(u3.x), e3.w, acc.x))));
        acc.y = fmaf(bf2f(u0.y), e0.w, fmaf(bf2f(u1.y), e1.w, fmaf(bf2f(u2.y), e2.w, fmaf(bf2f(u3.y), e3.w, acc.y))));
        acc.z = fmaf(bf2f(u0.z), e0.w, fmaf(bf2f(u1.z), e1.w, fmaf(bf2f(u2.z), e2.w, fmaf(bf2f(u3.z), e3.w, acc.z))));
        acc.w = fmaf(bf2f(u0.w), e0.w, fmaf(bf2f(u1.w), e1.w, fmaf(bf2f(u2.w), e2.w, fmaf(bf2f(u3.w), e3.w, acc.w))));
    }
    for (; k < end; ++k) {
        Edge e = edges[k];
        ushort4 u = ((const ushort4*)(tab + (long long)e.s * D_FEAT))[lane];
        acc.x = fmaf(bf2f(u.x), e.w, acc.x);
        acc.y = fmaf(bf2f(u.y), e.w, acc.y);
        acc.z = fmaf(bf2f(u.z), e.w, acc.z);
        acc.w = fmaf(bf2f(u.w), e.w, acc.w);
    }

    float r = lr[hop];
    ushort4 pu = ((const ushort4*)(tab + (long long)gid * D_FEAT))[lane];
    float4 o;
    o.x = acc.x * r + (1.0f - r) * bf2f(pu.x);
    o.y = acc.y * r + (1.0f - r) * bf2f(pu.y);
    o.z = acc.z * r + (1.0f - r) * bf2f(pu.z);
    o.w = acc.w * r + (1.0f - r) * bf2f(pu.w);
    ((float4*)(out + (long long)gid * OUT_STRIDE))[lane] = o;
    if (tab_next) {
        ushort4 ov;
        ov.x = f2bf(o.x); ov.y = f2bf(o.y); ov.z = f2bf(o.z); ov.w = f2bf(o.w);
        ((ushort4*)(tab_next + (long long)gid * D_FEAT))[lane] = ov;
    }
}

extern "C" void kernel_launch(void* const* d_in, const int* in_sizes, int n_in,
                              void* d_out, int out_size, void* d_ws, size_t ws_size,
                              hipStream_t stream) {
    const float* h   = (const float*)d_in[0];
    const float* dn  = (const float*)d_in[1];
    const int*   src = (const int*)d_in[2];
    const int*   dst = (const int*)d_in[3];
    const float* lr  = (const float*)d_in[4];
    float* out = (float*)d_out;

    // workspace carve-up (16B-aligned chunks first)
    char* base = (char*)d_ws;
    Edge* edges = (Edge*)base;                    base += (size_t)N_EDGES * sizeof(Edge);
    unsigned short* tabA = (unsigned short*)base; base += (size_t)N_NODES * D_FEAT * sizeof(unsigned short);
    unsigned short* tabB = (unsigned short*)base; base += (size_t)N_NODES * D_FEAT * sizeof(unsigned short);
    int* off      = (int*)base;                   base += (N_NODES + 1) * sizeof(int);
    int* deg      = (int*)base;                   base += N_NODES * sizeof(int);
    int* cursor   = (int*)base;                   base += N_NODES * sizeof(int);
    int* partials = (int*)base;                   base += NBLK_SCAN * sizeof(int);

    zero_deg_kernel<<<NBLK_SCAN, SCAN_B, 0, stream>>>(deg);
    hist_kernel<<<EB_BLOCKS, 256, 0, stream>>>(dst, deg);
    scanA_kernel<<<NBLK_SCAN, SCAN_B, 0, stream>>>(deg, off, partials);
    scanB_kernel<<<1, SCAN_B, 0, stream>>>(partials);
    scanC_kernel<<<NBLK_SCAN, SCAN_B, 0, stream>>>(off, partials, cursor);
    scatter_kernel<<<EB_BLOCKS, 256, 0, stream>>>(src, dst, dn, off, cursor, edges);
    f32_to_bf16_kernel<<<(F2B_VEC + 255) / 256, 256, 0, stream>>>(h, tabA);

    // 4 fused hops (bf16 ping-pong tables)
    const int HB = (N_NODES + GPB - 1) / GPB;  // 6250 blocks of 192 threads
    unsigned short* cur = tabA;
    unsigned short* nxt = tabB;
    for (int hop = 0; hop < HOP_NUM; ++hop) {
        unsigned short* wr = (hop == HOP_NUM - 1) ? (unsigned short*)nullptr : nxt;
        spmm_gather_kernel<<<HB, HOP_BLOCK, 0, stream>>>(cur, off, edges, lr, hop,
                                                         out + hop * D_FEAT, wr);
        unsigned short* t = cur; cur = nxt; nxt = t;
    }
}